// Round 1
// baseline (307.596 us; speedup 1.0000x reference)
//
#include <hip/hip_runtime.h>

typedef unsigned short u16x8 __attribute__((ext_vector_type(8)));
typedef short          s16x8 __attribute__((ext_vector_type(8)));
typedef float          f32x4 __attribute__((ext_vector_type(4)));

#define NTOK   4096      // B*S
#define DMODEL 1024
#define NEXP   16
#define TOPK   2

// RNE float->bf16 (inputs are normal floats, no NaN handling needed)
__device__ inline unsigned short f2bf(float f) {
    unsigned int x = __float_as_uint(f);
    x += 0x7fffu + ((x >> 16) & 1u);
    return (unsigned short)(x >> 16);
}

// ---------------- routing: fp64 scores, softmax, top-2 ----------------
__global__ void routing_kernel(const float* __restrict__ u,
                               const float* __restrict__ cent,
                               const float* __restrict__ ebias,
                               float* __restrict__ topk_g,
                               int*   __restrict__ topk_i) {
    int wid  = threadIdx.x >> 6;
    int lane = threadIdx.x & 63;
    int t = blockIdx.x * 4 + wid;
    const float* urow = u + (size_t)t * DMODEL;

    double acc[NEXP];
#pragma unroll
    for (int e = 0; e < NEXP; e++) acc[e] = 0.0;

    for (int j = 0; j < DMODEL / 64; j++) {
        int d = j * 64 + lane;
        double uv = (double)urow[d];
#pragma unroll
        for (int e = 0; e < NEXP; e++)
            acc[e] += uv * (double)cent[e * DMODEL + d];
    }
#pragma unroll
    for (int e = 0; e < NEXP; e++) {
        for (int off = 32; off; off >>= 1)
            acc[e] += __shfl_xor(acc[e], off);
    }
    if (lane == 0) {
        double mx = -1e300;
#pragma unroll
        for (int e = 0; e < NEXP; e++) {
            acc[e] += (double)ebias[e];
            if (acc[e] > mx) mx = acc[e];
        }
        double ex[NEXP], den = 0.0;
#pragma unroll
        for (int e = 0; e < NEXP; e++) { ex[e] = exp(acc[e] - mx); den += ex[e]; }
        int i1 = -1, i2 = -1;
        double v1 = -1.0, v2 = -1.0;
        for (int e = 0; e < NEXP; e++) {
            double v = ex[e];
            if (v > v1)      { v2 = v1; i2 = i1; v1 = v; i1 = e; }
            else if (v > v2) { v2 = v;  i2 = e; }
        }
        topk_g[t * 2 + 0] = (float)(v1 / den);
        topk_g[t * 2 + 1] = (float)(v2 / den);
        topk_i[t * 2 + 0] = i1;
        topk_i[t * 2 + 1] = i2;
    }
}

__global__ void init_counts(int* cnt) {
    if (threadIdx.x < 64) cnt[threadIdx.x] = 0;  // zero (padded) count region
}

__global__ void build_lists(const float* __restrict__ topk_g,
                            const int*   __restrict__ topk_i,
                            int* __restrict__ cnt,
                            int* __restrict__ tokL,
                            float* __restrict__ gateL) {
    int id = blockIdx.x * 256 + threadIdx.x;   // 0..8191
    if (id >= NTOK * TOPK) return;
    int t = id >> 1;
    int e = topk_i[id];
    float g = topk_g[id];
    int pos = atomicAdd(&cnt[e], 1);
    tokL[e * NTOK + pos]  = t;
    gateL[e * NTOK + pos] = g;
}

// ---------------- conversions ----------------
__global__ void conv_bf16_kernel(const float* __restrict__ src,
                                 unsigned short* __restrict__ dst, int n8) {
    int id = blockIdx.x * 256 + threadIdx.x;
    if (id >= n8) return;
    size_t base = (size_t)id * 8;
    u16x8 o;
#pragma unroll
    for (int i = 0; i < 8; i++) o[i] = f2bf(src[base + i]);
    *(u16x8*)&dst[base] = o;
}

__global__ void conv_wsum_kernel(const float* __restrict__ Ws,
                                 const float* __restrict__ bs,
                                 unsigned short* __restrict__ wsum,
                                 float* __restrict__ bsum) {
    int id = blockIdx.x * 256 + threadIdx.x;  // n8 = 131072
    if (id < 131072) {
        size_t base = (size_t)id * 8;
        u16x8 o;
#pragma unroll
        for (int i = 0; i < 8; i++)
            o[i] = f2bf(Ws[base + i] + Ws[(size_t)DMODEL * DMODEL + base + i]);
        *(u16x8*)&wsum[base] = o;
    }
    if (id < DMODEL) bsum[id] = bs[id] + bs[DMODEL + id];
}

// ---------------- GEMMs: BM=64, BN=128, BK=64, 4 waves (2x2) ----------------
// LDS stride 72 elems (144B = 9*16B): 16B-aligned rows, 2-way (free) bank pattern.

__global__ __launch_bounds__(256)
void shared_gemm(const unsigned short* __restrict__ ub,    // [4096][1024] bf16
                 const unsigned short* __restrict__ wsum,  // [1024][1024] bf16
                 const float* __restrict__ bsum,           // [1024]
                 const float* __restrict__ u,              // fp32
                 float* __restrict__ out) {
    __shared__ __align__(16) unsigned short As[64][72];
    __shared__ __align__(16) unsigned short Bs[128][72];

    int t = threadIdx.x;
    int m0 = blockIdx.x * 64;
    int n0 = blockIdx.y * 128;
    int lane = t & 63, wid = t >> 6;
    int wm = wid >> 1, wn = wid & 1;
    int lr = lane & 15, lk = (lane >> 4) * 8;
    int sr = t >> 3, sc = (t & 7) * 8;

    f32x4 acc[2][4];
#pragma unroll
    for (int i = 0; i < 2; i++)
#pragma unroll
        for (int j = 0; j < 4; j++)
#pragma unroll
            for (int v = 0; v < 4; v++) acc[i][j][v] = 0.0f;

    for (int k0 = 0; k0 < DMODEL; k0 += 64) {
#pragma unroll
        for (int p = 0; p < 2; p++) {
            int r = p * 32 + sr;
            *(u16x8*)&As[r][sc] =
                *(const u16x8*)&ub[(size_t)(m0 + r) * DMODEL + k0 + sc];
        }
#pragma unroll
        for (int p = 0; p < 4; p++) {
            int r = p * 32 + sr;
            *(u16x8*)&Bs[r][sc] =
                *(const u16x8*)&wsum[(size_t)(n0 + r) * DMODEL + k0 + sc];
        }
        __syncthreads();
#pragma unroll
        for (int ks = 0; ks < 2; ks++) {
            int kk = ks * 32 + lk;
            s16x8 a[2], b[4];
#pragma unroll
            for (int i = 0; i < 2; i++) a[i] = *(s16x8*)&As[wm * 32 + i * 16 + lr][kk];
#pragma unroll
            for (int j = 0; j < 4; j++) b[j] = *(s16x8*)&Bs[wn * 64 + j * 16 + lr][kk];
#pragma unroll
            for (int i = 0; i < 2; i++)
#pragma unroll
                for (int j = 0; j < 4; j++)
                    acc[i][j] = __builtin_amdgcn_mfma_f32_16x16x32_bf16(
                        a[i], b[j], acc[i][j], 0, 0, 0);
        }
        __syncthreads();
    }

    int rbase = m0 + wm * 32 + (lane >> 4) * 4;
    int cbase = n0 + wn * 64 + lr;
#pragma unroll
    for (int i = 0; i < 2; i++) {
#pragma unroll
        for (int j = 0; j < 4; j++) {
            int col = cbase + j * 16;
            float bv = bsum[col];
#pragma unroll
            for (int v = 0; v < 4; v++) {
                int row = rbase + i * 16 + v;
                size_t idx = (size_t)row * DMODEL + col;
                out[idx] = u[idx] + 0.5f * (acc[i][j][v] + bv);
            }
        }
    }
}

__global__ __launch_bounds__(256)
void routed_gemm(const unsigned short* __restrict__ ub,   // [4096][1024] bf16
                 const unsigned short* __restrict__ wr,   // [16][1024][1024] bf16
                 const float* __restrict__ br,            // [16][1024]
                 const int*   __restrict__ cnt,
                 const int*   __restrict__ tokL,          // [16][4096]
                 const float* __restrict__ gateL,
                 float* __restrict__ out) {
    int e  = blockIdx.x >> 6;
    int mt = blockIdx.x & 63;
    int count = cnt[e];
    if (mt * 64 >= count) return;

    __shared__ __align__(16) unsigned short As[64][72];
    __shared__ __align__(16) unsigned short Bs[128][72];

    int t = threadIdx.x;
    int n0 = blockIdx.y * 128;
    int lane = t & 63, wid = t >> 6;
    int wm = wid >> 1, wn = wid & 1;
    int lr = lane & 15, lk = (lane >> 4) * 8;
    int sr = t >> 3, sc = (t & 7) * 8;

    const int* tl = tokL + e * NTOK;
    int gi0 = mt * 64 + sr;
    int gi1 = mt * 64 + 32 + sr;
    int tok0 = tl[gi0 < count ? gi0 : count - 1];
    int tok1 = tl[gi1 < count ? gi1 : count - 1];
    const unsigned short* we = wr + (size_t)e * DMODEL * DMODEL;

    f32x4 acc[2][4];
#pragma unroll
    for (int i = 0; i < 2; i++)
#pragma unroll
        for (int j = 0; j < 4; j++)
#pragma unroll
            for (int v = 0; v < 4; v++) acc[i][j][v] = 0.0f;

    for (int k0 = 0; k0 < DMODEL; k0 += 64) {
        *(u16x8*)&As[sr][sc] =
            *(const u16x8*)&ub[(size_t)tok0 * DMODEL + k0 + sc];
        *(u16x8*)&As[32 + sr][sc] =
            *(const u16x8*)&ub[(size_t)tok1 * DMODEL + k0 + sc];
#pragma unroll
        for (int p = 0; p < 4; p++) {
            int r = p * 32 + sr;
            *(u16x8*)&Bs[r][sc] =
                *(const u16x8*)&we[(size_t)(n0 + r) * DMODEL + k0 + sc];
        }
        __syncthreads();
#pragma unroll
        for (int ks = 0; ks < 2; ks++) {
            int kk = ks * 32 + lk;
            s16x8 a[2], b[4];
#pragma unroll
            for (int i = 0; i < 2; i++) a[i] = *(s16x8*)&As[wm * 32 + i * 16 + lr][kk];
#pragma unroll
            for (int j = 0; j < 4; j++) b[j] = *(s16x8*)&Bs[wn * 64 + j * 16 + lr][kk];
#pragma unroll
            for (int i = 0; i < 2; i++)
#pragma unroll
                for (int j = 0; j < 4; j++)
                    acc[i][j] = __builtin_amdgcn_mfma_f32_16x16x32_bf16(
                        a[i], b[j], acc[i][j], 0, 0, 0);
        }
        __syncthreads();
    }

    int rloc = wm * 32 + (lane >> 4) * 4;
    int cb = n0 + wn * 64 + lr;
#pragma unroll
    for (int i = 0; i < 2; i++) {
#pragma unroll
        for (int v = 0; v < 4; v++) {
            int gi = mt * 64 + rloc + i * 16 + v;
            if (gi < count) {
                int tok = tl[gi];
                float g = gateL[e * NTOK + gi];
#pragma unroll
                for (int j = 0; j < 4; j++) {
                    int col = cb + j * 16;
                    atomicAdd(&out[(size_t)tok * DMODEL + col],
                              g * (acc[i][j][v] + br[e * DMODEL + col]));
                }
            }
        }
    }
}

extern "C" void kernel_launch(void* const* d_in, const int* in_sizes, int n_in,
                              void* d_out, int out_size, void* d_ws, size_t ws_size,
                              hipStream_t stream) {
    const float* u    = (const float*)d_in[0];
    const float* cent = (const float*)d_in[1];
    const float* eb   = (const float*)d_in[2];
    const float* Wr   = (const float*)d_in[3];
    const float* br   = (const float*)d_in[4];
    const float* Ws   = (const float*)d_in[5];
    const float* bs   = (const float*)d_in[6];
    float* out = (float*)d_out;

    char* ws = (char*)d_ws;
    size_t off = 0;
    auto take = [&](size_t b) { size_t o = off; off += (b + 255) & ~(size_t)255; return o; };
    float* topk_g = (float*)(ws + take(NTOK * TOPK * 4));
    int*   topk_i = (int*)  (ws + take(NTOK * TOPK * 4));
    int*   cnt    = (int*)  (ws + take(64 * 4));
    int*   tokL   = (int*)  (ws + take((size_t)NEXP * NTOK * 4));
    float* gateL  = (float*)(ws + take((size_t)NEXP * NTOK * 4));
    float* bsum   = (float*)(ws + take(DMODEL * 4));
    unsigned short* ub    = (unsigned short*)(ws + take((size_t)NTOK * DMODEL * 2));
    unsigned short* wsum  = (unsigned short*)(ws + take((size_t)DMODEL * DMODEL * 2));
    unsigned short* wr16  = (unsigned short*)(ws + take((size_t)NEXP * DMODEL * DMODEL * 2));

    routing_kernel<<<NTOK / 4, 256, 0, stream>>>(u, cent, eb, topk_g, topk_i);
    init_counts<<<1, 64, 0, stream>>>(cnt);
    build_lists<<<(NTOK * TOPK + 255) / 256, 256, 0, stream>>>(topk_g, topk_i, cnt, tokL, gateL);
    conv_bf16_kernel<<<(NTOK * DMODEL / 8 + 255) / 256, 256, 0, stream>>>(u, ub, NTOK * DMODEL / 8);
    conv_bf16_kernel<<<(NEXP * DMODEL * DMODEL / 8 + 255) / 256, 256, 0, stream>>>(
        Wr, wr16, NEXP * DMODEL * DMODEL / 8);
    conv_wsum_kernel<<<(DMODEL * DMODEL / 8 + 255) / 256, 256, 0, stream>>>(Ws, bs, wsum, bsum);
    shared_gemm<<<dim3(NTOK / 64, DMODEL / 128), 256, 0, stream>>>(ub, wsum, bsum, u, out);
    routed_gemm<<<dim3(NEXP * (NTOK / 64), DMODEL / 128), 256, 0, stream>>>(
        ub, wr16, br, cnt, tokL, gateL, out);
}